// Round 5
// baseline (312.837 us; speedup 1.0000x reference)
//
#include <hip/hip_runtime.h>

typedef _Float16 half8  __attribute__((ext_vector_type(8)));
typedef _Float16 half4  __attribute__((ext_vector_type(4)));
typedef float    float4v __attribute__((ext_vector_type(4)));
typedef float    float8v __attribute__((ext_vector_type(8)));

#define N_ROWS  65536   // 64*32*32
#define N_CODES 1024
#define DIM     256
#define BM      32      // rows per block
#define NBLKS   (N_ROWS / BM)   // 2048

// ---- prep: one wave per code. ||e||^2 and hi/lo f16 split written in MFMA
// B-fragment order (16x16x32): frag block b = nt*8 + ks holds 1024 halves:
// [hi 512][lo 512], chunk p = quad*16 + l15 -> code = nt*16+l15,
// k = ks*32 + quad*8 + j.
__global__ __launch_bounds__(64)
void vq_prep(const float* __restrict__ emb, float* __restrict__ e_norm,
             _Float16* __restrict__ e_frag) {
    const int c = blockIdx.x, lane = threadIdx.x;
    const int l15 = c & 15, nt = c >> 4;
    float4v v = ((const float4v*)(emb + (size_t)c * DIM))[lane];
    half4 h, l;
    float ss = 0.f;
    #pragma unroll
    for (int j = 0; j < 4; ++j) {
        float x = v[j];
        ss += x * x;
        _Float16 hh = (_Float16)x;
        h[j] = hh;
        l[j] = (_Float16)(x - (float)hh);
    }
    // this lane's 4 elements: k = lane*4 .. +3
    const int ks = lane >> 3, q = (lane >> 1) & 3, jb = (lane & 1) * 4;
    _Float16* p = e_frag + ((size_t)(nt * 8 + ks)) * 1024 + (q * 16 + l15) * 8 + jb;
    *(half4*)p = h;
    *(half4*)(p + 512) = l;
    #pragma unroll
    for (int m = 32; m >= 1; m >>= 1) ss += __shfl_xor(ss, m, 64);
    if (lane == 0) e_norm[c] = ss;
}

// ---- main: 256 threads (4 waves), BM=32 rows/block, full K in LDS (32 KB),
// ~38 KB LDS + <=170 regs/wave (64 AGPR acc + ~100 VGPR) -> 3 blocks/CU,
// 3 waves/SIMD: more co-resident wave diversity so one wave's B-load phase
// hides under another's MFMA burst. Inner structure identical to the
// measured-best round-3 kernel (compiler-scheduled loads, no manual dbuf,
// 8 independent nt chains, 3 separated hi/lo sweeps). Each wave: all 32
// rows x 256 codes in 2 passes of 128 codes (acc[2][8] = 64 AGPR).
__global__ __launch_bounds__(256, 3)
void vq_main(const float* __restrict__ z,
             const _Float16* __restrict__ e_frag,
             const float* __restrict__ e_norm,
             const float* __restrict__ emb,
             float* __restrict__ zq,
             float* __restrict__ idxf,
             int fused_gather) {
    __shared__ _Float16 sA[16 * 2 * 512];     // [mt*8+ks][hi|lo][512] = 32 KB (mt<2)
    __shared__ float    s_nrm[N_CODES];       // 4 KB
    __shared__ float2   s_best[BM][5];        // 4 wave slots + pad: 1.25 KB
    __shared__ int      s_idx[BM];

    const int t = threadIdx.x;
    const int w = t >> 6, lane = t & 63, quad = lane >> 4, l15 = lane & 15;
    const int rowblk = blockIdx.x * BM;

    s_nrm[t]       = e_norm[t];
    s_nrm[t + 256] = e_norm[t + 256];
    s_nrm[t + 512] = e_norm[t + 512];
    s_nrm[t + 768] = e_norm[t + 768];

    // ---- stage A: wave w stages mt = w&1, ks = (w>>1)*4 .. +3 (4 iters).
    // Global: 16 rows x 32-col chunks (128 B/row). LDS write = fragbase +
    // lane*16 B, contiguous per wave: conflict-free.
    {
        const int mt = w & 1;
        const int ksbase = (w >> 1) * 4;
        #pragma unroll
        for (int i = 0; i < 4; ++i) {
            const int ks = ksbase + i;
            const int row = mt * 16 + l15;
            const int col = ks * 32 + quad * 8;
            float8v v = *(const float8v*)(z + (size_t)(rowblk + row) * DIM + col);
            half8 h, lo;
            #pragma unroll
            for (int j = 0; j < 8; ++j) {
                float x = v[j];
                _Float16 hh = (_Float16)x;
                h[j] = hh;
                lo[j] = (_Float16)(x - (float)hh);
            }
            _Float16* p = sA + (size_t)((mt * 8 + ks) * 2) * 512 + lane * 8;
            *(half8*)p = h;
            *(half8*)(p + 512) = lo;
        }
    }
    __syncthreads();   // the only compute barrier

    for (int pass = 0; pass < 2; ++pass) {
        const int ntbase = w * 16 + pass * 8;
        float4v acc[2][8] = {};

        #pragma unroll
        for (int ks = 0; ks < 8; ++ks) {
            // B frags for 8 nt tiles (hi+lo), direct from L2-resident e_frag
            half8 bh[8], bl[8];
            #pragma unroll
            for (int nt = 0; nt < 8; ++nt) {
                const _Float16* bp = e_frag + ((size_t)((ntbase + nt) * 8 + ks)) * 1024 + lane * 8;
                bh[nt] = *(const half8*)bp;
                bl[nt] = *(const half8*)(bp + 512);
            }
            __builtin_amdgcn_s_setprio(1);
            #pragma unroll
            for (int mt = 0; mt < 2; ++mt) {
                const _Float16* ap = sA + (size_t)((mt * 8 + ks) * 2) * 512 + lane * 8;
                half8 ah = *(const half8*)ap;
                half8 al = *(const half8*)(ap + 512);
                // three separate nt-sweeps: dep chains on each acc are
                // 3 deep but spaced 8 apart -> MFMA pipe stays fed
                #pragma unroll
                for (int nt = 0; nt < 8; ++nt)
                    acc[mt][nt] = __builtin_amdgcn_mfma_f32_16x16x32_f16(ah, bh[nt], acc[mt][nt], 0, 0, 0);
                #pragma unroll
                for (int nt = 0; nt < 8; ++nt)
                    acc[mt][nt] = __builtin_amdgcn_mfma_f32_16x16x32_f16(ah, bl[nt], acc[mt][nt], 0, 0, 0);
                #pragma unroll
                for (int nt = 0; nt < 8; ++nt)
                    acc[mt][nt] = __builtin_amdgcn_mfma_f32_16x16x32_f16(al, bh[nt], acc[mt][nt], 0, 0, 0);
            }
            __builtin_amdgcn_s_setprio(0);
        }

        // ---- pass epilogue: score = ||e||^2 - 2*dot; per-row argmin.
        // C/D layout: col = lane&15, row = quad*4 + reg.
        float nrm[8]; int cg[8];
        #pragma unroll
        for (int nt = 0; nt < 8; ++nt) {
            cg[nt]  = (ntbase + nt) * 16 + l15;
            nrm[nt] = s_nrm[cg[nt]];
        }
        #pragma unroll
        for (int mt = 0; mt < 2; ++mt) {
            #pragma unroll
            for (int r = 0; r < 4; ++r) {
                float bs = nrm[0] - 2.0f * acc[mt][0][r]; int bi = cg[0];
                #pragma unroll
                for (int nt = 1; nt < 8; ++nt) {
                    float s = nrm[nt] - 2.0f * acc[mt][nt][r];
                    if (s < bs) { bs = s; bi = cg[nt]; }   // ascending codes: strict <
                }
                #pragma unroll
                for (int m = 1; m < 16; m <<= 1) {   // reduce the 16 l15 lanes (same row)
                    float s2 = __shfl_xor(bs, m, 64);
                    int   i2 = __shfl_xor(bi, m, 64);
                    if (s2 < bs || (s2 == bs && i2 < bi)) { bs = s2; bi = i2; }
                }
                if (l15 == 0) {
                    const int row = mt * 16 + quad * 4 + r;
                    if (pass == 0) {
                        float2 pr; pr.x = bs; pr.y = (float)bi;
                        s_best[row][w] = pr;
                    } else {
                        // running merge: later pass has strictly higher codes,
                        // so strict < keeps the lowest index on ties.
                        float2 pv = s_best[row][w];
                        if (bs < pv.x) {
                            float2 pr; pr.x = bs; pr.y = (float)bi;
                            s_best[row][w] = pr;
                        }
                    }
                }
            }
        }
    }
    __syncthreads();

    // ---- block reduce over 4 wave slots/row; write indices
    if (t < BM) {
        float2 p0 = s_best[t][0];
        float bs = p0.x, bi = p0.y;
        #pragma unroll
        for (int s = 1; s < 4; ++s) {
            float2 pv = s_best[t][s];
            if (pv.x < bs || (pv.x == bs && pv.y < bi)) { bs = pv.x; bi = pv.y; }
        }
        s_idx[t] = (int)bi;
        idxf[rowblk + t] = bi;
    }

    if (!fused_gather) return;
    __syncthreads();

    // ---- fused gather: 8 threads/row, 8 float4 each (32 rows, 256 threads)
    const float4v* emb4 = (const float4v*)emb;
    float4v* zq4 = (float4v*)zq;
    const int rr = t >> 3, cb = t & 7;
    const int code = s_idx[rr];
    #pragma unroll
    for (int i = 0; i < 8; ++i) {
        const int chunk = cb + i * 8;
        zq4[(size_t)(rowblk + rr) * 64 + chunk] = emb4[(size_t)code * 64 + chunk];
    }
}

// ---- fallback gather (only when e_frag had to live in d_out): wave per row
__global__ __launch_bounds__(256)
void vq_gather(const float* __restrict__ emb,
               const float* __restrict__ idxf,
               float* __restrict__ zq) {
    const int tid  = blockIdx.x * 256 + threadIdx.x;
    const int r    = tid >> 6;
    const int lane = tid & 63;
    const int idx  = (int)idxf[r];
    const float4* ep = (const float4*)(emb + (size_t)idx * DIM);
    ((float4*)(zq + (size_t)r * DIM))[lane] = ep[lane];
}

extern "C" void kernel_launch(void* const* d_in, const int* in_sizes, int n_in,
                              void* d_out, int out_size, void* d_ws, size_t ws_size,
                              hipStream_t stream) {
    const float* z   = (const float*)d_in[0];   // (64,32,32,256) fp32
    const float* emb = (const float*)d_in[1];   // (1024,256) fp32

    float* zq   = (float*)d_out;                        // output 0: 16,777,216 f
    float* idxf = zq + (size_t)N_ROWS * DIM;            // output 1: 65,536 f

    // scratch: e_norm (4 KB pad) + e_frag (1 MB)
    const size_t need = 4096 + (size_t)N_CODES * DIM * 2 * sizeof(_Float16);
    const int in_ws = (ws_size >= need);
    char* base = in_ws ? (char*)d_ws : (char*)d_out;    // fallback: zq area; then
                                                        // gather must be a later kernel
    float*    e_norm = (float*)base;
    _Float16* e_frag = (_Float16*)(base + 4096);

    vq_prep<<<N_CODES, 64, 0, stream>>>(emb, e_norm, e_frag);
    vq_main<<<NBLKS, 256, 0, stream>>>(z, e_frag, e_norm, emb, zq, idxf, in_ws);
    if (!in_ws)
        vq_gather<<<(N_ROWS * 64) / 256, 256, 0, stream>>>(emb, idxf, zq);
}

// Round 6
// 291.428 us; speedup vs baseline: 1.0735x; 1.0735x over previous
//
#include <hip/hip_runtime.h>

typedef _Float16 half8  __attribute__((ext_vector_type(8)));
typedef _Float16 half4  __attribute__((ext_vector_type(4)));
typedef float    float4v __attribute__((ext_vector_type(4)));
typedef float    float8v __attribute__((ext_vector_type(8)));

#define N_ROWS  65536   // 64*32*32
#define N_CODES 1024
#define DIM     256
#define BM      64      // rows per tile
#define NCOLS   8       // code-column blocks (128 codes each)
#define NGRP    128     // row groups
#define TILES   8       // row-tiles per block (NGRP*TILES*BM = N_ROWS)

// ---- prep: one wave per code. ||e||^2 and hi/lo f16 split written in MFMA
// B-fragment order (16x16x32): frag block b = nt*8 + ks holds 1024 halves:
// [hi 512][lo 512], chunk p = quad*16 + l15 -> code = nt*16+l15,
// k = ks*32 + quad*8 + j.
__global__ __launch_bounds__(64)
void vq_prep(const float* __restrict__ emb, float* __restrict__ e_norm,
             _Float16* __restrict__ e_frag) {
    const int c = blockIdx.x, lane = threadIdx.x;
    const int l15 = c & 15, nt = c >> 4;
    float4v v = ((const float4v*)(emb + (size_t)c * DIM))[lane];
    half4 h, l;
    float ss = 0.f;
    #pragma unroll
    for (int j = 0; j < 4; ++j) {
        float x = v[j];
        ss += x * x;
        _Float16 hh = (_Float16)x;
        h[j] = hh;
        l[j] = (_Float16)(x - (float)hh);
    }
    const int ks = lane >> 3, q = (lane >> 1) & 3, jb = (lane & 1) * 4;
    _Float16* p = e_frag + ((size_t)(nt * 8 + ks)) * 1024 + (q * 16 + l15) * 8 + jb;
    *(half4*)p = h;
    *(half4*)(p + 512) = l;
    #pragma unroll
    for (int m = 32; m >= 1; m >>= 1) ss += __shfl_xor(ss, m, 64);
    if (lane == 0) e_norm[c] = ss;
}

// ---- persistent-B main: grid = NCOLS(8) x NGRP(128). Block (c,g):
// c = blockIdx>>7, g = blockIdx&127 (so the 8 cols of a group share an XCD
// under round-robin dispatch -> z tile L2-dedup). Each wave holds B-frags
// for its 2 nt-tiles x 8 ks PERMANENTLY in registers (128 VGPR, loaded
// once: B L2 traffic drops 8x vs re-reading e_frag per row-block, which
// was the measured R3 limiter). Block streams TILES=8 row-tiles of 64 rows:
// stage A to LDS -> compute (acc[4 mt][2 nt]=32 AGPR, 3 hi/lo sweeps of 8
// independent tiles) -> per-row argmin over the block's 128 codes ->
// best[row][c]. 2 blocks/CU (64KB LDS, ~210 regs) so one block's stage
// hides under the other's MFMA stream.
__global__ __launch_bounds__(256, 2)
void vq_main_p(const float* __restrict__ z,
               const _Float16* __restrict__ e_frag,
               const float* __restrict__ e_norm,
               float2* __restrict__ best) {
    __shared__ _Float16 sA[32 * 2 * 512];     // [mt*8+ks][hi|lo][512] = 64 KB
    __shared__ float2   s_best[BM][5];        // 4 wave slots + pad

    const int t = threadIdx.x;
    const int w = t >> 6, lane = t & 63, quad = lane >> 4, l15 = lane & 15;
    const int c = blockIdx.x >> 7, g = blockIdx.x & (NGRP - 1);
    const int ntbase = c * 8 + w * 2;
    const int rowbase = g * (TILES * BM);

    // ---- persistent B: 2 nt x 8 ks, hi+lo = 128 VGPR, loaded once from L2
    half8 bh[2][8], bl[2][8];
    #pragma unroll
    for (int nt = 0; nt < 2; ++nt)
        #pragma unroll
        for (int ks = 0; ks < 8; ++ks) {
            const _Float16* bp = e_frag + ((size_t)((ntbase + nt) * 8 + ks)) * 1024 + lane * 8;
            bh[nt][ks] = *(const half8*)bp;
            bl[nt][ks] = *(const half8*)(bp + 512);
        }

    float nrm[2]; int cg[2];
    #pragma unroll
    for (int nt = 0; nt < 2; ++nt) {
        cg[nt]  = (ntbase + nt) * 16 + l15;
        nrm[nt] = e_norm[cg[nt]];
    }

    // ---- stage tile 0: wave w stages mt=w (16 rows x all 8 ks).
    // LDS write = fragbase + lane*16 B: conflict-free.
    {
        const int rowblk = rowbase;
        #pragma unroll
        for (int i = 0; i < 8; ++i) {
            const int row = w * 16 + l15;
            const int col = i * 32 + quad * 8;
            float8v v = *(const float8v*)(z + (size_t)(rowblk + row) * DIM + col);
            half8 h, lo;
            #pragma unroll
            for (int j = 0; j < 8; ++j) {
                float x = v[j];
                _Float16 hh = (_Float16)x;
                h[j] = hh;
                lo[j] = (_Float16)(x - (float)hh);
            }
            _Float16* p = sA + (size_t)((w * 8 + i) * 2) * 512 + lane * 8;
            *(half8*)p = h;
            *(half8*)(p + 512) = lo;
        }
    }

    for (int tt = 0; tt < TILES; ++tt) {
        __syncthreads();          // sA[tt] ready; prev s_best consumed

        float4v acc[4][2] = {};
        #pragma unroll
        for (int ks = 0; ks < 8; ++ks) {
            half8 ah[4], al[4];
            #pragma unroll
            for (int mt = 0; mt < 4; ++mt) {
                const _Float16* ap = sA + (size_t)((mt * 8 + ks) * 2) * 512 + lane * 8;
                ah[mt] = *(const half8*)ap;
                al[mt] = *(const half8*)(ap + 512);
            }
            __builtin_amdgcn_s_setprio(1);
            // 3 sweeps over 8 independent (mt,nt) tiles: dep chains 3-deep
            // at distance 8 -> MFMA pipe stays fed
            #pragma unroll
            for (int mt = 0; mt < 4; ++mt)
                #pragma unroll
                for (int nt = 0; nt < 2; ++nt)
                    acc[mt][nt] = __builtin_amdgcn_mfma_f32_16x16x32_f16(ah[mt], bh[nt][ks], acc[mt][nt], 0, 0, 0);
            #pragma unroll
            for (int mt = 0; mt < 4; ++mt)
                #pragma unroll
                for (int nt = 0; nt < 2; ++nt)
                    acc[mt][nt] = __builtin_amdgcn_mfma_f32_16x16x32_f16(ah[mt], bl[nt][ks], acc[mt][nt], 0, 0, 0);
            #pragma unroll
            for (int mt = 0; mt < 4; ++mt)
                #pragma unroll
                for (int nt = 0; nt < 2; ++nt)
                    acc[mt][nt] = __builtin_amdgcn_mfma_f32_16x16x32_f16(al[mt], bh[nt][ks], acc[mt][nt], 0, 0, 0);
            __builtin_amdgcn_s_setprio(0);
        }

        // ---- epilogue: score = ||e||^2 - 2*dot; per-row argmin over this
        // wave's 32 codes. C/D layout: col = lane&15, row = quad*4 + reg.
        #pragma unroll
        for (int mt = 0; mt < 4; ++mt) {
            #pragma unroll
            for (int r = 0; r < 4; ++r) {
                float bs = nrm[0] - 2.0f * acc[mt][0][r]; int bi = cg[0];
                float s1 = nrm[1] - 2.0f * acc[mt][1][r];
                if (s1 < bs) { bs = s1; bi = cg[1]; }    // ascending: strict <
                #pragma unroll
                for (int m = 1; m < 16; m <<= 1) {       // reduce 16 l15 lanes
                    float s2 = __shfl_xor(bs, m, 64);
                    int   i2 = __shfl_xor(bi, m, 64);
                    if (s2 < bs || (s2 == bs && i2 < bi)) { bs = s2; bi = i2; }
                }
                if (l15 == 0) {
                    float2 pr; pr.x = bs; pr.y = (float)bi;
                    s_best[mt * 16 + quad * 4 + r][w] = pr;
                }
            }
        }
        __syncthreads();          // s_best complete; all sA reads done

        // stage next tile (overwrites sA) while t<64 threads reduce
        if (tt + 1 < TILES) {
            const int rowblk = rowbase + (tt + 1) * BM;
            #pragma unroll
            for (int i = 0; i < 8; ++i) {
                const int row = w * 16 + l15;
                const int col = i * 32 + quad * 8;
                float8v v = *(const float8v*)(z + (size_t)(rowblk + row) * DIM + col);
                half8 h, lo;
                #pragma unroll
                for (int j = 0; j < 8; ++j) {
                    float x = v[j];
                    _Float16 hh = (_Float16)x;
                    h[j] = hh;
                    lo[j] = (_Float16)(x - (float)hh);
                }
                _Float16* p = sA + (size_t)((w * 8 + i) * 2) * 512 + lane * 8;
                *(half8*)p = h;
                *(half8*)(p + 512) = lo;
            }
        }
        if (t < BM) {
            float2 p0 = s_best[t][0];
            float bs = p0.x, bi = p0.y;
            #pragma unroll
            for (int s = 1; s < 4; ++s) {
                float2 pv = s_best[t][s];
                if (pv.x < bs || (pv.x == bs && pv.y < bi)) { bs = pv.x; bi = pv.y; }
            }
            float2 pr; pr.x = bs; pr.y = bi;
            best[(size_t)(rowbase + tt * BM + t) * NCOLS + c] = pr;
        }
    }
}

// ---- final: reduce 8 column candidates per row, write idx, gather zq.
// 4 waves/block = 4 rows; all lanes read best[r][lane&7] (broadcast dup),
// 3-step xor reduce within 8-groups converges every lane to the row min.
__global__ __launch_bounds__(256)
void vq_gather2(const float* __restrict__ emb,
                const float2* __restrict__ best,
                float* __restrict__ zq,
                float* __restrict__ idxf) {
    const int t = threadIdx.x, w = t >> 6, lane = t & 63;
    const int r = blockIdx.x * 4 + w;
    float2 pv = best[(size_t)r * NCOLS + (lane & 7)];
    float bs = pv.x, bi = pv.y;
    #pragma unroll
    for (int m = 1; m < 8; m <<= 1) {
        float s2 = __shfl_xor(bs, m, 64);
        float i2 = __shfl_xor(bi, m, 64);
        if (s2 < bs || (s2 == bs && i2 < bi)) { bs = s2; bi = i2; }
    }
    const int idx = (int)bi;
    if (lane == 0) idxf[r] = bi;
    ((float4*)(zq + (size_t)r * DIM))[lane] =
        ((const float4*)(emb + (size_t)idx * DIM))[lane];
}

// ============== fallback path (small workspace): R3 kernel verbatim ======
__global__ __launch_bounds__(256, 2)
void vq_main(const float* __restrict__ z,
             const _Float16* __restrict__ e_frag,
             const float* __restrict__ e_norm,
             const float* __restrict__ emb,
             float* __restrict__ zq,
             float* __restrict__ idxf,
             int fused_gather) {
    __shared__ _Float16 sA[32 * 2 * 512];
    __shared__ float    s_nrm[N_CODES];
    __shared__ float2   s_best[BM][5];
    __shared__ int      s_idx[BM];

    const int t = threadIdx.x;
    const int w = t >> 6, lane = t & 63, quad = lane >> 4, l15 = lane & 15;
    const int rowblk = blockIdx.x * BM;

    s_nrm[t]       = e_norm[t];
    s_nrm[t + 256] = e_norm[t + 256];
    s_nrm[t + 512] = e_norm[t + 512];
    s_nrm[t + 768] = e_norm[t + 768];

    #pragma unroll
    for (int i = 0; i < 8; ++i) {
        const int row = w * 16 + l15;
        const int col = i * 32 + quad * 8;
        float8v v = *(const float8v*)(z + (size_t)(rowblk + row) * DIM + col);
        half8 h, lo;
        #pragma unroll
        for (int j = 0; j < 8; ++j) {
            float x = v[j];
            _Float16 hh = (_Float16)x;
            h[j] = hh;
            lo[j] = (_Float16)(x - (float)hh);
        }
        _Float16* p = sA + (size_t)((w * 8 + i) * 2) * 512 + lane * 8;
        *(half8*)p = h;
        *(half8*)(p + 512) = lo;
    }
    __syncthreads();

    for (int pass = 0; pass < 2; ++pass) {
        const int ntbase = w * 16 + pass * 8;
        float4v acc[4][8] = {};

        #pragma unroll
        for (int ks = 0; ks < 8; ++ks) {
            half8 bh[8], bl[8];
            #pragma unroll
            for (int nt = 0; nt < 8; ++nt) {
                const _Float16* bp = e_frag + ((size_t)((ntbase + nt) * 8 + ks)) * 1024 + lane * 8;
                bh[nt] = *(const half8*)bp;
                bl[nt] = *(const half8*)(bp + 512);
            }
            __builtin_amdgcn_s_setprio(1);
            #pragma unroll
            for (int mt = 0; mt < 4; ++mt) {
                const _Float16* ap = sA + (size_t)((mt * 8 + ks) * 2) * 512 + lane * 8;
                half8 ah = *(const half8*)ap;
                half8 al = *(const half8*)(ap + 512);
                #pragma unroll
                for (int nt = 0; nt < 8; ++nt)
                    acc[mt][nt] = __builtin_amdgcn_mfma_f32_16x16x32_f16(ah, bh[nt], acc[mt][nt], 0, 0, 0);
                #pragma unroll
                for (int nt = 0; nt < 8; ++nt)
                    acc[mt][nt] = __builtin_amdgcn_mfma_f32_16x16x32_f16(ah, bl[nt], acc[mt][nt], 0, 0, 0);
                #pragma unroll
                for (int nt = 0; nt < 8; ++nt)
                    acc[mt][nt] = __builtin_amdgcn_mfma_f32_16x16x32_f16(al, bh[nt], acc[mt][nt], 0, 0, 0);
            }
            __builtin_amdgcn_s_setprio(0);
        }

        float nrm[8]; int cg[8];
        #pragma unroll
        for (int nt = 0; nt < 8; ++nt) {
            cg[nt]  = (ntbase + nt) * 16 + l15;
            nrm[nt] = s_nrm[cg[nt]];
        }
        #pragma unroll
        for (int mt = 0; mt < 4; ++mt) {
            #pragma unroll
            for (int r = 0; r < 4; ++r) {
                float bs = nrm[0] - 2.0f * acc[mt][0][r]; int bi = cg[0];
                #pragma unroll
                for (int nt = 1; nt < 8; ++nt) {
                    float s = nrm[nt] - 2.0f * acc[mt][nt][r];
                    if (s < bs) { bs = s; bi = cg[nt]; }
                }
                #pragma unroll
                for (int m = 1; m < 16; m <<= 1) {
                    float s2 = __shfl_xor(bs, m, 64);
                    int   i2 = __shfl_xor(bi, m, 64);
                    if (s2 < bs || (s2 == bs && i2 < bi)) { bs = s2; bi = i2; }
                }
                if (l15 == 0) {
                    const int row = mt * 16 + quad * 4 + r;
                    if (pass == 0) {
                        float2 pr; pr.x = bs; pr.y = (float)bi;
                        s_best[row][w] = pr;
                    } else {
                        float2 pv = s_best[row][w];
                        if (bs < pv.x) {
                            float2 pr; pr.x = bs; pr.y = (float)bi;
                            s_best[row][w] = pr;
                        }
                    }
                }
            }
        }
    }
    __syncthreads();

    if (t < BM) {
        float2 p0 = s_best[t][0];
        float bs = p0.x, bi = p0.y;
        #pragma unroll
        for (int s = 1; s < 4; ++s) {
            float2 pv = s_best[t][s];
            if (pv.x < bs || (pv.x == bs && pv.y < bi)) { bs = pv.x; bi = pv.y; }
        }
        s_idx[t] = (int)bi;
        idxf[rowblk + t] = bi;
    }

    if (!fused_gather) return;
    __syncthreads();

    const float4v* emb4 = (const float4v*)emb;
    float4v* zq4 = (float4v*)zq;
    const int rr = t >> 2, cb = t & 3;
    const int code = s_idx[rr];
    #pragma unroll
    for (int i = 0; i < 16; ++i) {
        const int chunk = cb + i * 4;
        zq4[(size_t)(rowblk + rr) * 64 + chunk] = emb4[(size_t)code * 64 + chunk];
    }
}

__global__ __launch_bounds__(256)
void vq_gather(const float* __restrict__ emb,
               const float* __restrict__ idxf,
               float* __restrict__ zq) {
    const int tid  = blockIdx.x * 256 + threadIdx.x;
    const int r    = tid >> 6;
    const int lane = tid & 63;
    const int idx  = (int)idxf[r];
    const float4* ep = (const float4*)(emb + (size_t)idx * DIM);
    ((float4*)(zq + (size_t)r * DIM))[lane] = ep[lane];
}

extern "C" void kernel_launch(void* const* d_in, const int* in_sizes, int n_in,
                              void* d_out, int out_size, void* d_ws, size_t ws_size,
                              hipStream_t stream) {
    const float* z   = (const float*)d_in[0];   // (64,32,32,256) fp32
    const float* emb = (const float*)d_in[1];   // (1024,256) fp32

    float* zq   = (float*)d_out;                        // output 0
    float* idxf = zq + (size_t)N_ROWS * DIM;            // output 1

    const size_t efrag_sz = (size_t)N_CODES * DIM * 2 * sizeof(_Float16); // 1 MB
    const size_t best_sz  = (size_t)N_ROWS * NCOLS * sizeof(float2);      // 4 MB
    const size_t need_p   = 4096 + efrag_sz + best_sz;

    if (ws_size >= need_p) {
        // persistent-B path
        float*    e_norm = (float*)d_ws;
        _Float16* e_frag = (_Float16*)((char*)d_ws + 4096);
        float2*   best   = (float2*)((char*)d_ws + 4096 + efrag_sz);
        vq_prep<<<N_CODES, 64, 0, stream>>>(emb, e_norm, e_frag);
        vq_main_p<<<NCOLS * NGRP, 256, 0, stream>>>(z, e_frag, e_norm, best);
        vq_gather2<<<N_ROWS / 4, 256, 0, stream>>>(emb, best, zq, idxf);
    } else {
        // fallback: measured-best R3 path
        const size_t need = 4096 + efrag_sz;
        const int in_ws = (ws_size >= need);
        char* base = in_ws ? (char*)d_ws : (char*)d_out;
        float*    e_norm = (float*)base;
        _Float16* e_frag = (_Float16*)(base + 4096);
        vq_prep<<<N_CODES, 64, 0, stream>>>(emb, e_norm, e_frag);
        vq_main<<<N_ROWS / BM, 256, 0, stream>>>(z, e_frag, e_norm, emb, zq, idxf, in_ws);
        if (!in_ws)
            vq_gather<<<(N_ROWS * 64) / 256, 256, 0, stream>>>(emb, idxf, zq);
    }
}

// Round 7
// 217.501 us; speedup vs baseline: 1.4383x; 1.3399x over previous
//
#include <hip/hip_runtime.h>

typedef _Float16 half8  __attribute__((ext_vector_type(8)));
typedef _Float16 half4  __attribute__((ext_vector_type(4)));
typedef float    float4v __attribute__((ext_vector_type(4)));
typedef float    float8v __attribute__((ext_vector_type(8)));

#define N_ROWS  65536   // 64*32*32
#define N_CODES 1024
#define DIM     256
#define BM      64      // rows per block
#define NBLKS   (N_ROWS / BM)   // 1024

// ---- prep: one wave per code. ||e||^2 and hi/lo f16 split written in MFMA
// B-fragment order (16x16x32): frag block b = nt*8 + ks holds 1024 halves:
// [hi 512][lo 512], chunk p = quad*16 + l15 -> code = nt*16+l15,
// k = ks*32 + quad*8 + j.  Also resets the rescore counter.
__global__ __launch_bounds__(64)
void vq_prep(const float* __restrict__ emb, float* __restrict__ e_norm,
             _Float16* __restrict__ e_frag, int* __restrict__ count) {
    const int c = blockIdx.x, lane = threadIdx.x;
    const int l15 = c & 15, nt = c >> 4;
    if (count && c == 0 && lane == 0) *count = 0;
    float4v v = ((const float4v*)(emb + (size_t)c * DIM))[lane];
    half4 h, l;
    float ss = 0.f;
    #pragma unroll
    for (int j = 0; j < 4; ++j) {
        float x = v[j];
        ss += x * x;
        _Float16 hh = (_Float16)x;
        h[j] = hh;
        l[j] = (_Float16)(x - (float)hh);
    }
    const int ks = lane >> 3, q = (lane >> 1) & 3, jb = (lane & 1) * 4;
    _Float16* p = e_frag + ((size_t)(nt * 8 + ks)) * 1024 + (q * 16 + l15) * 8 + jb;
    *(half4*)p = h;
    *(half4*)(p + 512) = l;
    #pragma unroll
    for (int m = 32; m >= 1; m >>= 1) ss += __shfl_xor(ss, m, 64);
    if (lane == 0) e_norm[c] = ss;
}

// ---- phase 1: hh-only screen. R3 structure (256 thr / 4 waves / BM=64 /
// full-K hi-only LDS / 1 staging barrier / compiler-scheduled loads) but
// ONE MFMA sweep (1/3 the MFMA work, 1/2 the B traffic). Tracks per-row
// (min1, idx1, min2); rows with min2-min1 <= T are flagged for exact
// rescore. T >= 2*E where E = 2*2.001*2^-11*||z||*||e||max rigorously
// bounds |approx - exact| (dropped zh*el + zl*e terms, Cauchy-Schwarz),
// so non-flagged rows provably have the exact argmin.
__global__ __launch_bounds__(256, 2)
void vq_screen(const float* __restrict__ z,
               const _Float16* __restrict__ e_frag,
               const float* __restrict__ e_norm,
               const float* __restrict__ emb,
               float* __restrict__ zq,
               float* __restrict__ idxf,
               int* __restrict__ count,
               int* __restrict__ list) {
    __shared__ _Float16 sA[32 * 512];         // hi only: [mt*8+ks][512] = 32 KB
    __shared__ float    s_nrm[N_CODES];       // 4 KB
    __shared__ float    s_znrm[BM];
    __shared__ float    s_red[4];
    __shared__ float4   s_best[BM][5];        // (m1, idx, m2, -) per wave slot
    __shared__ int      s_idx[BM];

    const int t = threadIdx.x;
    const int w = t >> 6, lane = t & 63, quad = lane >> 4, l15 = lane & 15;
    const int rowblk = blockIdx.x * BM;

    float n0 = e_norm[t], n1 = e_norm[t + 256], n2 = e_norm[t + 512], n3 = e_norm[t + 768];
    s_nrm[t] = n0; s_nrm[t + 256] = n1; s_nrm[t + 512] = n2; s_nrm[t + 768] = n3;
    float mx = fmaxf(fmaxf(n0, n1), fmaxf(n2, n3));
    #pragma unroll
    for (int m = 1; m < 64; m <<= 1) mx = fmaxf(mx, __shfl_xor(mx, m, 64));
    if (lane == 0) s_red[w] = mx;

    // ---- stage A (hi only) + per-row ||z||^2. wave w stages rows
    // w*16..w*16+15; LDS write = fragbase + lane*16 B: conflict-free.
    float ss = 0.f;
    #pragma unroll
    for (int i = 0; i < 8; ++i) {
        const int row = w * 16 + l15;
        const int col = i * 32 + quad * 8;
        float8v v = *(const float8v*)(z + (size_t)(rowblk + row) * DIM + col);
        half8 h;
        #pragma unroll
        for (int j = 0; j < 8; ++j) {
            float x = v[j];
            ss += x * x;
            h[j] = (_Float16)x;
        }
        *(half8*)(sA + (size_t)(w * 8 + i) * 512 + lane * 8) = h;
    }
    ss += __shfl_xor(ss, 16, 64);     // sum the 4 quads of the same row
    ss += __shfl_xor(ss, 32, 64);
    if (quad == 0) s_znrm[w * 16 + l15] = ss;
    __syncthreads();   // the only compute barrier

    for (int pass = 0; pass < 2; ++pass) {
        const int ntbase = w * 16 + pass * 8;
        float4v acc[4][8] = {};

        #pragma unroll
        for (int ks = 0; ks < 8; ++ks) {
            half8 bh[8];
            #pragma unroll
            for (int nt = 0; nt < 8; ++nt)
                bh[nt] = *(const half8*)(e_frag + ((size_t)((ntbase + nt) * 8 + ks)) * 1024 + lane * 8);
            __builtin_amdgcn_s_setprio(1);
            #pragma unroll
            for (int mt = 0; mt < 4; ++mt) {
                half8 ah = *(const half8*)(sA + (size_t)(mt * 8 + ks) * 512 + lane * 8);
                #pragma unroll
                for (int nt = 0; nt < 8; ++nt)
                    acc[mt][nt] = __builtin_amdgcn_mfma_f32_16x16x32_f16(ah, bh[nt], acc[mt][nt], 0, 0, 0);
            }
            __builtin_amdgcn_s_setprio(0);
        }

        // ---- epilogue: per-row (min1, idx, min2) over this wave's 128 codes.
        // C/D layout: col = lane&15, row = quad*4 + reg.
        float nrm[8]; int cg[8];
        #pragma unroll
        for (int nt = 0; nt < 8; ++nt) {
            cg[nt]  = (ntbase + nt) * 16 + l15;
            nrm[nt] = s_nrm[cg[nt]];
        }
        #pragma unroll
        for (int mt = 0; mt < 4; ++mt) {
            #pragma unroll
            for (int r = 0; r < 4; ++r) {
                float m1 = nrm[0] - 2.0f * acc[mt][0][r]; int i1 = cg[0];
                float m2 = 1e30f;
                #pragma unroll
                for (int nt = 1; nt < 8; ++nt) {
                    float s = nrm[nt] - 2.0f * acc[mt][nt][r];
                    if (s < m1) { m2 = m1; m1 = s; i1 = cg[nt]; }  // ascending: strict <
                    else m2 = fminf(m2, s);
                }
                #pragma unroll
                for (int m = 1; m < 16; m <<= 1) {   // merge 16 l15 lanes (same row)
                    float o1 = __shfl_xor(m1, m, 64);
                    int   oi = __shfl_xor(i1, m, 64);
                    float o2 = __shfl_xor(m2, m, 64);
                    if (o1 < m1 || (o1 == m1 && oi < i1)) {
                        m2 = fminf(m1, o2); m1 = o1; i1 = oi;
                    } else {
                        m2 = fminf(m2, o1);
                    }
                }
                if (l15 == 0) {
                    const int row = mt * 16 + quad * 4 + r;
                    if (pass == 0) {
                        float4 pr; pr.x = m1; pr.y = (float)i1; pr.z = m2; pr.w = 0.f;
                        s_best[row][w] = pr;
                    } else {
                        // merge with pass-0 (lower codes stored first: ties keep stored)
                        float4 pv = s_best[row][w];
                        float4 pr;
                        if (m1 < pv.x) { pr.x = m1; pr.y = (float)i1; pr.z = fminf(pv.x, m2); }
                        else           { pr.x = pv.x; pr.y = pv.y;     pr.z = fminf(pv.z, m1); }
                        pr.w = 0.f;
                        s_best[row][w] = pr;
                    }
                }
            }
        }
    }
    __syncthreads();

    // ---- block reduce over 4 wave slots/row; write idx; flag tight rows
    if (t < BM) {
        float4 b0 = s_best[t][0];
        float m1 = b0.x, fi = b0.y, m2 = b0.z;
        #pragma unroll
        for (int s = 1; s < 4; ++s) {     // slots in ascending-code order
            float4 bv = s_best[t][s];
            if (bv.x < m1 || (bv.x == m1 && bv.y < fi)) {
                m2 = fminf(m1, bv.z); m1 = bv.x; fi = bv.y;
            } else {
                m2 = fminf(m2, bv.x);
            }
        }
        s_idx[t] = (int)fi;
        idxf[rowblk + t] = fi;
        float emax = sqrtf(fmaxf(fmaxf(s_red[0], s_red[1]), fmaxf(s_red[2], s_red[3])));
        float T = 0.005f * sqrtf(s_znrm[t]) * emax + 0.05f;   // >= 2*error bound
        if (m2 - m1 <= T) {
            int pos = atomicAdd(count, 1);
            list[pos] = rowblk + t;
        }
    }
    __syncthreads();

    // ---- fused gather: 4 threads/row, 16 float4 each
    const float4v* emb4 = (const float4v*)emb;
    float4v* zq4 = (float4v*)zq;
    const int rr = t >> 2, cb = t & 3;
    const int code = s_idx[rr];
    #pragma unroll
    for (int i = 0; i < 16; ++i) {
        const int chunk = cb + i * 4;
        zq4[(size_t)(rowblk + rr) * 64 + chunk] = emb4[(size_t)code * 64 + chunk];
    }
}

// ---- phase 2: exact 3-sweep rescore of flagged rows (R3 kernel + row
// indirection). Grid is worst-case; blocks beyond count exit immediately.
// Padded slots duplicate the last row (identical concurrent writes: benign).
__global__ __launch_bounds__(256, 2)
void vq_exact(const float* __restrict__ z,
              const _Float16* __restrict__ e_frag,
              const float* __restrict__ e_norm,
              const float* __restrict__ emb,
              float* __restrict__ zq,
              float* __restrict__ idxf,
              const int* __restrict__ count,
              const int* __restrict__ list) {
    const int cnt = *count;
    const int base = blockIdx.x * BM;
    if (base >= cnt) return;

    __shared__ _Float16 sA[32 * 2 * 512];     // [mt*8+ks][hi|lo][512] = 64 KB
    __shared__ float    s_nrm[N_CODES];
    __shared__ float2   s_best[BM][5];
    __shared__ int      s_idx[BM];
    __shared__ int      s_rows[BM];

    const int t = threadIdx.x;
    const int w = t >> 6, lane = t & 63, quad = lane >> 4, l15 = lane & 15;

    if (t < BM) {
        int slot = base + t;
        s_rows[t] = list[slot < cnt ? slot : cnt - 1];
    }
    s_nrm[t]       = e_norm[t];
    s_nrm[t + 256] = e_norm[t + 256];
    s_nrm[t + 512] = e_norm[t + 512];
    s_nrm[t + 768] = e_norm[t + 768];
    __syncthreads();

    #pragma unroll
    for (int i = 0; i < 8; ++i) {
        const int row = w * 16 + l15;
        const int grow = s_rows[row];
        const int col = i * 32 + quad * 8;
        float8v v = *(const float8v*)(z + (size_t)grow * DIM + col);
        half8 h, lo;
        #pragma unroll
        for (int j = 0; j < 8; ++j) {
            float x = v[j];
            _Float16 hh = (_Float16)x;
            h[j] = hh;
            lo[j] = (_Float16)(x - (float)hh);
        }
        _Float16* p = sA + (size_t)((w * 8 + i) * 2) * 512 + lane * 8;
        *(half8*)p = h;
        *(half8*)(p + 512) = lo;
    }
    __syncthreads();

    for (int pass = 0; pass < 2; ++pass) {
        const int ntbase = w * 16 + pass * 8;
        float4v acc[4][8] = {};

        #pragma unroll
        for (int ks = 0; ks < 8; ++ks) {
            half8 bh[8], bl[8];
            #pragma unroll
            for (int nt = 0; nt < 8; ++nt) {
                const _Float16* bp = e_frag + ((size_t)((ntbase + nt) * 8 + ks)) * 1024 + lane * 8;
                bh[nt] = *(const half8*)bp;
                bl[nt] = *(const half8*)(bp + 512);
            }
            __builtin_amdgcn_s_setprio(1);
            #pragma unroll
            for (int mt = 0; mt < 4; ++mt) {
                const _Float16* ap = sA + (size_t)((mt * 8 + ks) * 2) * 512 + lane * 8;
                half8 ah = *(const half8*)ap;
                half8 al = *(const half8*)(ap + 512);
                #pragma unroll
                for (int nt = 0; nt < 8; ++nt)
                    acc[mt][nt] = __builtin_amdgcn_mfma_f32_16x16x32_f16(ah, bh[nt], acc[mt][nt], 0, 0, 0);
                #pragma unroll
                for (int nt = 0; nt < 8; ++nt)
                    acc[mt][nt] = __builtin_amdgcn_mfma_f32_16x16x32_f16(ah, bl[nt], acc[mt][nt], 0, 0, 0);
                #pragma unroll
                for (int nt = 0; nt < 8; ++nt)
                    acc[mt][nt] = __builtin_amdgcn_mfma_f32_16x16x32_f16(al, bh[nt], acc[mt][nt], 0, 0, 0);
            }
            __builtin_amdgcn_s_setprio(0);
        }

        float nrm[8]; int cg[8];
        #pragma unroll
        for (int nt = 0; nt < 8; ++nt) {
            cg[nt]  = (ntbase + nt) * 16 + l15;
            nrm[nt] = s_nrm[cg[nt]];
        }
        #pragma unroll
        for (int mt = 0; mt < 4; ++mt) {
            #pragma unroll
            for (int r = 0; r < 4; ++r) {
                float bs = nrm[0] - 2.0f * acc[mt][0][r]; int bi = cg[0];
                #pragma unroll
                for (int nt = 1; nt < 8; ++nt) {
                    float s = nrm[nt] - 2.0f * acc[mt][nt][r];
                    if (s < bs) { bs = s; bi = cg[nt]; }
                }
                #pragma unroll
                for (int m = 1; m < 16; m <<= 1) {
                    float s2 = __shfl_xor(bs, m, 64);
                    int   i2 = __shfl_xor(bi, m, 64);
                    if (s2 < bs || (s2 == bs && i2 < bi)) { bs = s2; bi = i2; }
                }
                if (l15 == 0) {
                    const int row = mt * 16 + quad * 4 + r;
                    if (pass == 0) {
                        float2 pr; pr.x = bs; pr.y = (float)bi;
                        s_best[row][w] = pr;
                    } else {
                        float2 pv = s_best[row][w];
                        if (bs < pv.x) {
                            float2 pr; pr.x = bs; pr.y = (float)bi;
                            s_best[row][w] = pr;
                        }
                    }
                }
            }
        }
    }
    __syncthreads();

    if (t < BM) {
        float2 p0 = s_best[t][0];
        float bs = p0.x, bi = p0.y;
        #pragma unroll
        for (int s = 1; s < 4; ++s) {
            float2 pv = s_best[t][s];
            if (pv.x < bs || (pv.x == bs && pv.y < bi)) { bs = pv.x; bi = pv.y; }
        }
        s_idx[t] = (int)bi;
        idxf[s_rows[t]] = bi;
    }
    __syncthreads();

    const float4v* emb4 = (const float4v*)emb;
    float4v* zq4 = (float4v*)zq;
    const int rr = t >> 2, cb = t & 3;
    const int grow = s_rows[rr];
    const int code = s_idx[rr];
    #pragma unroll
    for (int i = 0; i < 16; ++i) {
        const int chunk = cb + i * 4;
        zq4[(size_t)grow * 64 + chunk] = emb4[(size_t)code * 64 + chunk];
    }
}

// ============== fallback path (small workspace): R3 kernel verbatim ======
__global__ __launch_bounds__(256, 2)
void vq_main(const float* __restrict__ z,
             const _Float16* __restrict__ e_frag,
             const float* __restrict__ e_norm,
             const float* __restrict__ emb,
             float* __restrict__ zq,
             float* __restrict__ idxf,
             int fused_gather) {
    __shared__ _Float16 sA[32 * 2 * 512];
    __shared__ float    s_nrm[N_CODES];
    __shared__ float2   s_best[BM][5];
    __shared__ int      s_idx[BM];

    const int t = threadIdx.x;
    const int w = t >> 6, lane = t & 63, quad = lane >> 4, l15 = lane & 15;
    const int rowblk = blockIdx.x * BM;

    s_nrm[t]       = e_norm[t];
    s_nrm[t + 256] = e_norm[t + 256];
    s_nrm[t + 512] = e_norm[t + 512];
    s_nrm[t + 768] = e_norm[t + 768];

    #pragma unroll
    for (int i = 0; i < 8; ++i) {
        const int row = w * 16 + l15;
        const int col = i * 32 + quad * 8;
        float8v v = *(const float8v*)(z + (size_t)(rowblk + row) * DIM + col);
        half8 h, lo;
        #pragma unroll
        for (int j = 0; j < 8; ++j) {
            float x = v[j];
            _Float16 hh = (_Float16)x;
            h[j] = hh;
            lo[j] = (_Float16)(x - (float)hh);
        }
        _Float16* p = sA + (size_t)((w * 8 + i) * 2) * 512 + lane * 8;
        *(half8*)p = h;
        *(half8*)(p + 512) = lo;
    }
    __syncthreads();

    for (int pass = 0; pass < 2; ++pass) {
        const int ntbase = w * 16 + pass * 8;
        float4v acc[4][8] = {};

        #pragma unroll
        for (int ks = 0; ks < 8; ++ks) {
            half8 bh[8], bl[8];
            #pragma unroll
            for (int nt = 0; nt < 8; ++nt) {
                const _Float16* bp = e_frag + ((size_t)((ntbase + nt) * 8 + ks)) * 1024 + lane * 8;
                bh[nt] = *(const half8*)bp;
                bl[nt] = *(const half8*)(bp + 512);
            }
            __builtin_amdgcn_s_setprio(1);
            #pragma unroll
            for (int mt = 0; mt < 4; ++mt) {
                const _Float16* ap = sA + (size_t)((mt * 8 + ks) * 2) * 512 + lane * 8;
                half8 ah = *(const half8*)ap;
                half8 al = *(const half8*)(ap + 512);
                #pragma unroll
                for (int nt = 0; nt < 8; ++nt)
                    acc[mt][nt] = __builtin_amdgcn_mfma_f32_16x16x32_f16(ah, bh[nt], acc[mt][nt], 0, 0, 0);
                #pragma unroll
                for (int nt = 0; nt < 8; ++nt)
                    acc[mt][nt] = __builtin_amdgcn_mfma_f32_16x16x32_f16(ah, bl[nt], acc[mt][nt], 0, 0, 0);
                #pragma unroll
                for (int nt = 0; nt < 8; ++nt)
                    acc[mt][nt] = __builtin_amdgcn_mfma_f32_16x16x32_f16(al, bh[nt], acc[mt][nt], 0, 0, 0);
            }
            __builtin_amdgcn_s_setprio(0);
        }

        float nrm[8]; int cg[8];
        #pragma unroll
        for (int nt = 0; nt < 8; ++nt) {
            cg[nt]  = (ntbase + nt) * 16 + l15;
            nrm[nt] = s_nrm[cg[nt]];
        }
        #pragma unroll
        for (int mt = 0; mt < 4; ++mt) {
            #pragma unroll
            for (int r = 0; r < 4; ++r) {
                float bs = nrm[0] - 2.0f * acc[mt][0][r]; int bi = cg[0];
                #pragma unroll
                for (int nt = 1; nt < 8; ++nt) {
                    float s = nrm[nt] - 2.0f * acc[mt][nt][r];
                    if (s < bs) { bs = s; bi = cg[nt]; }
                }
                #pragma unroll
                for (int m = 1; m < 16; m <<= 1) {
                    float s2 = __shfl_xor(bs, m, 64);
                    int   i2 = __shfl_xor(bi, m, 64);
                    if (s2 < bs || (s2 == bs && i2 < bi)) { bs = s2; bi = i2; }
                }
                if (l15 == 0) {
                    const int row = mt * 16 + quad * 4 + r;
                    if (pass == 0) {
                        float2 pr; pr.x = bs; pr.y = (float)bi;
                        s_best[row][w] = pr;
                    } else {
                        float2 pv = s_best[row][w];
                        if (bs < pv.x) {
                            float2 pr; pr.x = bs; pr.y = (float)bi;
                            s_best[row][w] = pr;
                        }
                    }
                }
            }
        }
    }
    __syncthreads();

    if (t < BM) {
        float2 p0 = s_best[t][0];
        float bs = p0.x, bi = p0.y;
        #pragma unroll
        for (int s = 1; s < 4; ++s) {
            float2 pv = s_best[t][s];
            if (pv.x < bs || (pv.x == bs && pv.y < bi)) { bs = pv.x; bi = pv.y; }
        }
        s_idx[t] = (int)bi;
        idxf[rowblk + t] = bi;
    }

    if (!fused_gather) return;
    __syncthreads();

    const float4v* emb4 = (const float4v*)emb;
    float4v* zq4 = (float4v*)zq;
    const int rr = t >> 2, cb = t & 3;
    const int code = s_idx[rr];
    #pragma unroll
    for (int i = 0; i < 16; ++i) {
        const int chunk = cb + i * 4;
        zq4[(size_t)(rowblk + rr) * 64 + chunk] = emb4[(size_t)code * 64 + chunk];
    }
}

__global__ __launch_bounds__(256)
void vq_gather(const float* __restrict__ emb,
               const float* __restrict__ idxf,
               float* __restrict__ zq) {
    const int tid  = blockIdx.x * 256 + threadIdx.x;
    const int r    = tid >> 6;
    const int lane = tid & 63;
    const int idx  = (int)idxf[r];
    const float4* ep = (const float4*)(emb + (size_t)idx * DIM);
    ((float4*)(zq + (size_t)r * DIM))[lane] = ep[lane];
}

extern "C" void kernel_launch(void* const* d_in, const int* in_sizes, int n_in,
                              void* d_out, int out_size, void* d_ws, size_t ws_size,
                              hipStream_t stream) {
    const float* z   = (const float*)d_in[0];   // (64,32,32,256) fp32
    const float* emb = (const float*)d_in[1];   // (1024,256) fp32

    float* zq   = (float*)d_out;                        // output 0
    float* idxf = zq + (size_t)N_ROWS * DIM;            // output 1

    const size_t efrag_sz = (size_t)N_CODES * DIM * 2 * sizeof(_Float16); // 1 MB
    const size_t list_sz  = (size_t)N_ROWS * sizeof(int);                 // 256 KB
    const size_t need_p   = 4096 + efrag_sz + 4096 + list_sz;

    if (ws_size >= need_p) {
        // screen + exact-rescore path
        float*    e_norm = (float*)d_ws;
        _Float16* e_frag = (_Float16*)((char*)d_ws + 4096);
        int*      count  = (int*)((char*)d_ws + 4096 + efrag_sz);
        int*      list   = (int*)((char*)d_ws + 4096 + efrag_sz + 4096);
        vq_prep<<<N_CODES, 64, 0, stream>>>(emb, e_norm, e_frag, count);
        vq_screen<<<NBLKS, 256, 0, stream>>>(z, e_frag, e_norm, emb, zq, idxf, count, list);
        vq_exact<<<NBLKS, 256, 0, stream>>>(z, e_frag, e_norm, emb, zq, idxf, count, list);
    } else {
        // fallback: measured-best R3 path
        const size_t need = 4096 + efrag_sz;
        const int in_ws = (ws_size >= need);
        char* base = in_ws ? (char*)d_ws : (char*)d_out;
        float*    e_norm = (float*)base;
        _Float16* e_frag = (_Float16*)(base + 4096);
        vq_prep<<<N_CODES, 64, 0, stream>>>(emb, e_norm, e_frag, (int*)0);
        vq_main<<<NBLKS, 256, 0, stream>>>(z, e_frag, e_norm, emb, zq, idxf, in_ws);
        if (!in_ws)
            vq_gather<<<(N_ROWS * 64) / 256, 256, 0, stream>>>(emb, idxf, zq);
    }
}